// Round 1
// baseline (8448.347 us; speedup 1.0000x reference)
//
#include <hip/hip_runtime.h>
#include <hip/hip_bf16.h>

typedef unsigned short u16;
typedef __bf16 v8bf __attribute__((ext_vector_type(8)));
typedef float v4f __attribute__((ext_vector_type(4)));

#define B_SZ 8
#define S_LEN 1024
#define IN_DIM 256
#define DMODEL 512
#define NHEAD 8
#define DK 64
#define FF_DIM 2048
#define MROWS (B_SZ * S_LEN)   // 8192

__device__ __forceinline__ u16 f2bf(float f) {
    unsigned int x = __float_as_uint(f);
    unsigned int r = (x + 0x7fffu + ((x >> 16) & 1u)) >> 16;
    return (u16)r;
}

// ---------------- elementwise f32 -> bf16 (inputs matrix) ----------------
__global__ __launch_bounds__(256) void conv_bf16_kernel(const float* __restrict__ in,
                                                        u16* __restrict__ out, int n4) {
    int i = blockIdx.x * 256 + threadIdx.x;
    if (i < n4) {
        float4 v = ((const float4*)in)[i];
        ushort4 o;
        o.x = f2bf(v.x); o.y = f2bf(v.y); o.z = f2bf(v.z); o.w = f2bf(v.w);
        ((ushort4*)out)[i] = o;
    }
}

// ------------- batched transpose+convert: (K,N) f32 -> (N,K) bf16 -------------
struct TDesc { const float* src; u16* dst; int K; int N; };
struct TArgs { TDesc d[13]; };

__global__ void transpose_conv_kernel(TArgs args) {
    TDesc t = args.d[blockIdx.z];
    int k0 = blockIdx.x * 32, n0 = blockIdx.y * 32;
    if (k0 >= t.K || n0 >= t.N) return;
    __shared__ float tile[32][33];
    int tx = threadIdx.x, ty = threadIdx.y;
#pragma unroll
    for (int j = 0; j < 4; j++) {
        int k = k0 + ty + j * 8;
        tile[ty + j * 8][tx] = t.src[(size_t)k * t.N + n0 + tx];
    }
    __syncthreads();
#pragma unroll
    for (int j = 0; j < 4; j++) {
        int n = n0 + ty + j * 8;
        t.dst[(size_t)n * t.K + k0 + tx] = f2bf(tile[tx][ty + j * 8]);
    }
}

// ---------------- LayerNorm: fp32 in -> bf16 (or fp32) out ----------------
// one wave per row, 4 rows per block
template <bool OUT_BF16>
__global__ __launch_bounds__(256) void ln_kernel(const float* __restrict__ x,
                                                 const float* __restrict__ g,
                                                 const float* __restrict__ b,
                                                 void* __restrict__ out) {
    int row = blockIdx.x * 4 + (threadIdx.x >> 6);
    int lane = threadIdx.x & 63;
    const float4* xr = (const float4*)(x + (size_t)row * DMODEL);
    float4 v0 = xr[lane], v1 = xr[lane + 64];
    float s = v0.x + v0.y + v0.z + v0.w + v1.x + v1.y + v1.z + v1.w;
    float sq = v0.x * v0.x + v0.y * v0.y + v0.z * v0.z + v0.w * v0.w +
               v1.x * v1.x + v1.y * v1.y + v1.z * v1.z + v1.w * v1.w;
#pragma unroll
    for (int m = 1; m < 64; m <<= 1) {
        s += __shfl_xor(s, m);
        sq += __shfl_xor(sq, m);
    }
    float mean = s * (1.0f / DMODEL);
    float var = sq * (1.0f / DMODEL) - mean * mean;
    float rstd = rsqrtf(var + 1e-5f);
    const float4* g4 = (const float4*)g;
    const float4* b4 = (const float4*)b;
    float4 ga = g4[lane], gb = g4[lane + 64], ba = b4[lane], bb = b4[lane + 64];
    float4 r0, r1;
    r0.x = (v0.x - mean) * rstd * ga.x + ba.x;
    r0.y = (v0.y - mean) * rstd * ga.y + ba.y;
    r0.z = (v0.z - mean) * rstd * ga.z + ba.z;
    r0.w = (v0.w - mean) * rstd * ga.w + ba.w;
    r1.x = (v1.x - mean) * rstd * gb.x + bb.x;
    r1.y = (v1.y - mean) * rstd * gb.y + bb.y;
    r1.z = (v1.z - mean) * rstd * gb.z + bb.z;
    r1.w = (v1.w - mean) * rstd * gb.w + bb.w;
    if (OUT_BF16) {
        ushort4 o0, o1;
        o0.x = f2bf(r0.x); o0.y = f2bf(r0.y); o0.z = f2bf(r0.z); o0.w = f2bf(r0.w);
        o1.x = f2bf(r1.x); o1.y = f2bf(r1.y); o1.z = f2bf(r1.z); o1.w = f2bf(r1.w);
        ((ushort4*)out)[(size_t)row * 128 + lane] = o0;
        ((ushort4*)out)[(size_t)row * 128 + 64 + lane] = o1;
    } else {
        ((float4*)out)[(size_t)row * 128 + lane] = r0;
        ((float4*)out)[(size_t)row * 128 + 64 + lane] = r1;
    }
}

// ---------------- bf16 MFMA GEMM:  Out = A(MxK) @ Bt(NxK)^T + bias -------------
// MODE 0: fp32 out (+bias)                      [QKV projections]
// MODE 1: fp32 out (+bias +sinusoid PE)         [input projection]
// MODE 2: bf16 out (+bias, ReLU)                [FFN1]
// MODE 3: fp32 out (+bias + residual R)         [O-proj, FFN2]
template <int MODE>
__global__ __launch_bounds__(256) void gemm_kernel(const u16* __restrict__ A,
                                                   const u16* __restrict__ Bt,
                                                   const float* __restrict__ bias,
                                                   const float* __restrict__ R,
                                                   void* __restrict__ Out,
                                                   int M, int N, int K) {
    constexpr int LDK = 40;  // 32 + 8 pad (keeps 16B alignment, breaks bank stride)
    __shared__ u16 As[64 * LDK];
    __shared__ u16 Bs[64 * LDK];
    int tid = threadIdx.x;
    int n0 = blockIdx.x * 64, m0 = blockIdx.y * 64;
    int w = tid >> 6, lane = tid & 63;
    int wr = (w >> 1) * 32, wc = (w & 1) * 32;
    int lr = lane & 15, lq = lane >> 4;

    v4f zero = {0.f, 0.f, 0.f, 0.f};
    v4f acc[2][2];
    acc[0][0] = zero; acc[0][1] = zero; acc[1][0] = zero; acc[1][1] = zero;

    int arow = tid >> 2, acol = (tid & 3) * 8;
    const u16* Aptr = A + (size_t)(m0 + arow) * K + acol;
    const u16* Bptr = Bt + (size_t)(n0 + arow) * K + acol;
    u16* AsW = &As[arow * LDK + acol];
    u16* BsW = &Bs[arow * LDK + acol];

    for (int k0 = 0; k0 < K; k0 += 32) {
        v8bf av = *(const v8bf*)Aptr;
        v8bf bv = *(const v8bf*)Bptr;
        __syncthreads();
        *(v8bf*)AsW = av;
        *(v8bf*)BsW = bv;
        __syncthreads();
        v8bf a0 = *(const v8bf*)&As[(wr + lr) * LDK + lq * 8];
        v8bf a1 = *(const v8bf*)&As[(wr + 16 + lr) * LDK + lq * 8];
        v8bf b0 = *(const v8bf*)&Bs[(wc + lr) * LDK + lq * 8];
        v8bf b1 = *(const v8bf*)&Bs[(wc + 16 + lr) * LDK + lq * 8];
        acc[0][0] = __builtin_amdgcn_mfma_f32_16x16x32_bf16(a0, b0, acc[0][0], 0, 0, 0);
        acc[0][1] = __builtin_amdgcn_mfma_f32_16x16x32_bf16(a0, b1, acc[0][1], 0, 0, 0);
        acc[1][0] = __builtin_amdgcn_mfma_f32_16x16x32_bf16(a1, b0, acc[1][0], 0, 0, 0);
        acc[1][1] = __builtin_amdgcn_mfma_f32_16x16x32_bf16(a1, b1, acc[1][1], 0, 0, 0);
        Aptr += 32;
        Bptr += 32;
    }

#pragma unroll
    for (int mt = 0; mt < 2; mt++) {
#pragma unroll
        for (int nt = 0; nt < 2; nt++) {
            int col = n0 + wc + nt * 16 + lr;
            float bcol = bias[col];
#pragma unroll
            for (int reg = 0; reg < 4; reg++) {
                int row = m0 + wr + mt * 16 + lq * 4 + reg;
                float val = acc[mt][nt][reg] + bcol;
                if (MODE == 1) {
                    int sPos = row & (S_LEN - 1);
                    float freq = expf((float)(col & ~1) * (-0.017988946039015984f));
                    float ang = (float)sPos * freq;
                    val += (col & 1) ? cosf(ang) : sinf(ang);
                }
                if (MODE == 2) val = fmaxf(val, 0.0f);
                if (MODE == 3) val += R[(size_t)row * N + col];
                if (MODE == 2)
                    ((u16*)Out)[(size_t)row * N + col] = f2bf(val);
                else
                    ((float*)Out)[(size_t)row * N + col] = val;
            }
        }
    }
}

// ---------------- attention: one block per (b, h, q) ----------------
// Q,K,V fp32 (B,S,D) layout with head slice at cols [h*64, h*64+64); O bf16 same layout
__global__ __launch_bounds__(256) void attn_kernel(const float* __restrict__ Q,
                                                   const float* __restrict__ K,
                                                   const float* __restrict__ V,
                                                   const float* __restrict__ rb,
                                                   const int* __restrict__ lengths,
                                                   u16* __restrict__ O) {
    int q = blockIdx.x, h = blockIdx.y, b = blockIdx.z;
    int tid = threadIdx.x;
    __shared__ float sc[S_LEN];
    __shared__ float red[256];
    __shared__ float qs[DK];
    int len = lengths[b];
    size_t base = ((size_t)b * S_LEN) * DMODEL + h * DK;
    if (tid < DK) qs[tid] = Q[base + (size_t)q * DMODEL + tid];
    __syncthreads();

    const float* rbh = rb + h * 127;
    for (int k = tid; k < S_LEN; k += 256) {
        const float4* Kr = (const float4*)(K + base + (size_t)k * DMODEL);
        float dot = 0.f;
#pragma unroll
        for (int i = 0; i < 16; i++) {
            float4 kv = Kr[i];
            float4 qv = ((const float4*)qs)[i];
            dot += qv.x * kv.x + qv.y * kv.y + qv.z * kv.z + qv.w * kv.w;
        }
        int r = q - k;
        r = r < -63 ? -63 : (r > 63 ? 63 : r);
        float sv = dot * 0.125f + rbh[r + 63];
        sc[k] = (k < len) ? sv : -__builtin_inff();
    }
    __syncthreads();

    // max reduce
    float lm = -__builtin_inff();
    for (int k = tid; k < S_LEN; k += 256) lm = fmaxf(lm, sc[k]);
    red[tid] = lm;
    __syncthreads();
    for (int st = 128; st > 0; st >>= 1) {
        if (tid < st) red[tid] = fmaxf(red[tid], red[tid + st]);
        __syncthreads();
    }
    float mx = red[0];
    __syncthreads();

    // exp + sum reduce
    float lsum = 0.f;
    for (int k = tid; k < S_LEN; k += 256) {
        float p = __expf(sc[k] - mx);
        sc[k] = p;
        lsum += p;
    }
    red[tid] = lsum;
    __syncthreads();
    for (int st = 128; st > 0; st >>= 1) {
        if (tid < st) red[tid] += red[tid + st];
        __syncthreads();
    }
    float inv = 1.0f / red[0];
    __syncthreads();

    // P @ V : thread t handles dim (t&63), key chunk (t>>6)*256..+256
    int d = tid & 63, c = tid >> 6;
    const float* Vb = V + base + d;
    float acc = 0.f;
    int kend = c * 256 + 256;
    for (int k = c * 256; k < kend; k++) acc += sc[k] * Vb[(size_t)k * DMODEL];
    red[tid] = acc;
    __syncthreads();
    if (tid < 64) {
        float o = (red[tid] + red[tid + 64] + red[tid + 128] + red[tid + 192]) * inv;
        O[base + (size_t)q * DMODEL + tid] = f2bf(o);
    }
}

extern "C" void kernel_launch(void* const* d_in, const int* in_sizes, int n_in,
                              void* d_out, int out_size, void* d_ws, size_t ws_size,
                              hipStream_t stream) {
    const float* inputs   = (const float*)d_in[0];
    const int*   lengths  = (const int*)d_in[1];
    const float* W_in     = (const float*)d_in[2];
    const float* b_in     = (const float*)d_in[3];
    const float* Wq       = (const float*)d_in[4];
    const float* bq       = (const float*)d_in[5];
    const float* Wk       = (const float*)d_in[6];
    const float* bk       = (const float*)d_in[7];
    const float* Wv       = (const float*)d_in[8];
    const float* bv       = (const float*)d_in[9];
    const float* Wo       = (const float*)d_in[10];
    const float* bo       = (const float*)d_in[11];
    const float* rel_bias = (const float*)d_in[12];
    const float* W1       = (const float*)d_in[13];
    const float* b1       = (const float*)d_in[14];
    const float* W2       = (const float*)d_in[15];
    const float* b2       = (const float*)d_in[16];
    const float* g1       = (const float*)d_in[17];
    const float* be1      = (const float*)d_in[18];
    const float* g2       = (const float*)d_in[19];
    const float* be2      = (const float*)d_in[20];
    const float* gf       = (const float*)d_in[21];
    const float* bef      = (const float*)d_in[22];

    // ---- workspace layout ----
    char* ws = (char*)d_ws;
    float* xbuf = (float*)ws;          ws += (size_t)MROWS * DMODEL * 4;   // residual fp32
    u16* hbuf   = (u16*)ws;            ws += (size_t)MROWS * DMODEL * 2;   // LN output bf16
    u16* aobuf  = (u16*)ws;            ws += (size_t)MROWS * DMODEL * 2;   // attn output bf16
    float* qbuf = (float*)ws;                                              // union region:
    float* kbuf = qbuf + (size_t)MROWS * DMODEL;                           //  q/k/v fp32 OR
    float* vbuf = kbuf + (size_t)MROWS * DMODEL;                           //  FFN intermediate
    u16* tbuf   = (u16*)qbuf;          ws += (size_t)MROWS * DMODEL * 4 * 3;
    u16* inbf   = (u16*)ws;            ws += (size_t)MROWS * IN_DIM * 2;   // bf16 inputs
    u16* wt_in  = (u16*)ws;            ws += (size_t)DMODEL * IN_DIM * 2;
    u16 *wtq[2], *wtk[2], *wtv[2], *wto[2], *wt1[2], *wt2[2];
    for (int l = 0; l < 2; l++) { wtq[l] = (u16*)ws; ws += (size_t)DMODEL * DMODEL * 2; }
    for (int l = 0; l < 2; l++) { wtk[l] = (u16*)ws; ws += (size_t)DMODEL * DMODEL * 2; }
    for (int l = 0; l < 2; l++) { wtv[l] = (u16*)ws; ws += (size_t)DMODEL * DMODEL * 2; }
    for (int l = 0; l < 2; l++) { wto[l] = (u16*)ws; ws += (size_t)DMODEL * DMODEL * 2; }
    for (int l = 0; l < 2; l++) { wt1[l] = (u16*)ws; ws += (size_t)FF_DIM * DMODEL * 2; }
    for (int l = 0; l < 2; l++) { wt2[l] = (u16*)ws; ws += (size_t)DMODEL * FF_DIM * 2; }

    // ---- weight prep descriptors ----
    TArgs ta;
    int ti = 0;
    ta.d[ti++] = {W_in, wt_in, IN_DIM, DMODEL};
    for (int l = 0; l < 2; l++) ta.d[ti++] = {Wq + (size_t)l * DMODEL * DMODEL, wtq[l], DMODEL, DMODEL};
    for (int l = 0; l < 2; l++) ta.d[ti++] = {Wk + (size_t)l * DMODEL * DMODEL, wtk[l], DMODEL, DMODEL};
    for (int l = 0; l < 2; l++) ta.d[ti++] = {Wv + (size_t)l * DMODEL * DMODEL, wtv[l], DMODEL, DMODEL};
    for (int l = 0; l < 2; l++) ta.d[ti++] = {Wo + (size_t)l * DMODEL * DMODEL, wto[l], DMODEL, DMODEL};
    // note: one QKVO slot used above per l; remaining two groups:
    // (13 total: 1 + 8 + 2 + 2)
    for (int l = 0; l < 2; l++) ta.d[ti++] = {W1 + (size_t)l * DMODEL * FF_DIM, wt1[l], DMODEL, FF_DIM};
    // W2 handled below
    // fix: we already have 1+8+2 = 11, add W2 x2:
    for (int l = 0; l < 2; l++) ta.d[ti++] = {W2 + (size_t)l * FF_DIM * DMODEL, wt2[l], FF_DIM, DMODEL};

    conv_bf16_kernel<<<dim3((MROWS * IN_DIM / 4 + 255) / 256), 256, 0, stream>>>(
        inputs, inbf, MROWS * IN_DIM / 4);
    transpose_conv_kernel<<<dim3(64, 64, 13), dim3(32, 8), 0, stream>>>(ta);

    // input projection + PE -> fp32 residual
    gemm_kernel<1><<<dim3(DMODEL / 64, MROWS / 64), 256, 0, stream>>>(
        inbf, wt_in, b_in, nullptr, xbuf, MROWS, DMODEL, IN_DIM);

    for (int l = 0; l < 2; l++) {
        ln_kernel<true><<<MROWS / 4, 256, 0, stream>>>(xbuf, g1 + l * DMODEL, be1 + l * DMODEL, hbuf);
        gemm_kernel<0><<<dim3(DMODEL / 64, MROWS / 64), 256, 0, stream>>>(
            hbuf, wtq[l], bq + l * DMODEL, nullptr, qbuf, MROWS, DMODEL, DMODEL);
        gemm_kernel<0><<<dim3(DMODEL / 64, MROWS / 64), 256, 0, stream>>>(
            hbuf, wtk[l], bk + l * DMODEL, nullptr, kbuf, MROWS, DMODEL, DMODEL);
        gemm_kernel<0><<<dim3(DMODEL / 64, MROWS / 64), 256, 0, stream>>>(
            hbuf, wtv[l], bv + l * DMODEL, nullptr, vbuf, MROWS, DMODEL, DMODEL);
        attn_kernel<<<dim3(S_LEN, NHEAD, B_SZ), 256, 0, stream>>>(
            qbuf, kbuf, vbuf, rel_bias + (size_t)l * NHEAD * 127, lengths, aobuf);
        gemm_kernel<3><<<dim3(DMODEL / 64, MROWS / 64), 256, 0, stream>>>(
            aobuf, wto[l], bo + l * DMODEL, xbuf, xbuf, MROWS, DMODEL, DMODEL);
        ln_kernel<true><<<MROWS / 4, 256, 0, stream>>>(xbuf, g2 + l * DMODEL, be2 + l * DMODEL, hbuf);
        gemm_kernel<2><<<dim3(FF_DIM / 64, MROWS / 64), 256, 0, stream>>>(
            hbuf, wt1[l], b1 + l * FF_DIM, nullptr, tbuf, MROWS, FF_DIM, DMODEL);
        gemm_kernel<3><<<dim3(DMODEL / 64, MROWS / 64), 256, 0, stream>>>(
            tbuf, wt2[l], b2 + l * DMODEL, xbuf, xbuf, MROWS, DMODEL, FF_DIM);
    }
    ln_kernel<false><<<MROWS / 4, 256, 0, stream>>>(xbuf, gf, bef, d_out);
}

// Round 2
// 601.426 us; speedup vs baseline: 14.0472x; 14.0472x over previous
//
#include <hip/hip_runtime.h>
#include <hip/hip_bf16.h>

typedef unsigned short u16;
typedef __bf16 v8bf __attribute__((ext_vector_type(8)));
typedef float v4f __attribute__((ext_vector_type(4)));

#define B_SZ 8
#define S_LEN 1024
#define IN_DIM 256
#define DMODEL 512
#define NHEAD 8
#define DK 64
#define FF_DIM 2048
#define MROWS (B_SZ * S_LEN)   // 8192

__device__ __forceinline__ u16 f2bf(float f) {
    unsigned int x = __float_as_uint(f);
    unsigned int r = (x + 0x7fffu + ((x >> 16) & 1u)) >> 16;
    return (u16)r;
}

// ---------------- elementwise f32 -> bf16 (inputs matrix) ----------------
__global__ __launch_bounds__(256) void conv_bf16_kernel(const float* __restrict__ in,
                                                        u16* __restrict__ out, int n4) {
    int i = blockIdx.x * 256 + threadIdx.x;
    if (i < n4) {
        float4 v = ((const float4*)in)[i];
        ushort4 o;
        o.x = f2bf(v.x); o.y = f2bf(v.y); o.z = f2bf(v.z); o.w = f2bf(v.w);
        ((ushort4*)out)[i] = o;
    }
}

// ------------- batched transpose+convert: (K,N) f32 -> (N,K) bf16 -------------
struct TDesc { const float* src; u16* dst; int K; int N; };
struct TArgs { TDesc d[13]; };

__global__ void transpose_conv_kernel(TArgs args) {
    TDesc t = args.d[blockIdx.z];
    int k0 = blockIdx.x * 32, n0 = blockIdx.y * 32;
    if (k0 >= t.K || n0 >= t.N) return;
    __shared__ float tile[32][33];
    int tx = threadIdx.x, ty = threadIdx.y;
#pragma unroll
    for (int j = 0; j < 4; j++) {
        int k = k0 + ty + j * 8;
        tile[ty + j * 8][tx] = t.src[(size_t)k * t.N + n0 + tx];
    }
    __syncthreads();
#pragma unroll
    for (int j = 0; j < 4; j++) {
        int n = n0 + ty + j * 8;
        t.dst[(size_t)n * t.K + k0 + tx] = f2bf(tile[tx][ty + j * 8]);
    }
}

// ---------------- LayerNorm: fp32 in -> bf16 (or fp32) out ----------------
template <bool OUT_BF16>
__global__ __launch_bounds__(256) void ln_kernel(const float* __restrict__ x,
                                                 const float* __restrict__ g,
                                                 const float* __restrict__ b,
                                                 void* __restrict__ out) {
    int row = blockIdx.x * 4 + (threadIdx.x >> 6);
    int lane = threadIdx.x & 63;
    const float4* xr = (const float4*)(x + (size_t)row * DMODEL);
    float4 v0 = xr[lane], v1 = xr[lane + 64];
    float s = v0.x + v0.y + v0.z + v0.w + v1.x + v1.y + v1.z + v1.w;
    float sq = v0.x * v0.x + v0.y * v0.y + v0.z * v0.z + v0.w * v0.w +
               v1.x * v1.x + v1.y * v1.y + v1.z * v1.z + v1.w * v1.w;
#pragma unroll
    for (int m = 1; m < 64; m <<= 1) {
        s += __shfl_xor(s, m);
        sq += __shfl_xor(sq, m);
    }
    float mean = s * (1.0f / DMODEL);
    float var = sq * (1.0f / DMODEL) - mean * mean;
    float rstd = rsqrtf(var + 1e-5f);
    const float4* g4 = (const float4*)g;
    const float4* b4 = (const float4*)b;
    float4 ga = g4[lane], gb = g4[lane + 64], ba = b4[lane], bb = b4[lane + 64];
    float4 r0, r1;
    r0.x = (v0.x - mean) * rstd * ga.x + ba.x;
    r0.y = (v0.y - mean) * rstd * ga.y + ba.y;
    r0.z = (v0.z - mean) * rstd * ga.z + ba.z;
    r0.w = (v0.w - mean) * rstd * ga.w + ba.w;
    r1.x = (v1.x - mean) * rstd * gb.x + bb.x;
    r1.y = (v1.y - mean) * rstd * gb.y + bb.y;
    r1.z = (v1.z - mean) * rstd * gb.z + bb.z;
    r1.w = (v1.w - mean) * rstd * gb.w + bb.w;
    if (OUT_BF16) {
        ushort4 o0, o1;
        o0.x = f2bf(r0.x); o0.y = f2bf(r0.y); o0.z = f2bf(r0.z); o0.w = f2bf(r0.w);
        o1.x = f2bf(r1.x); o1.y = f2bf(r1.y); o1.z = f2bf(r1.z); o1.w = f2bf(r1.w);
        ((ushort4*)out)[(size_t)row * 128 + lane] = o0;
        ((ushort4*)out)[(size_t)row * 128 + 64 + lane] = o1;
    } else {
        ((float4*)out)[(size_t)row * 128 + lane] = r0;
        ((float4*)out)[(size_t)row * 128 + 64 + lane] = r1;
    }
}

// ---------------- bf16 MFMA GEMM:  Out = A(MxK) @ Bt(NxK)^T + bias -------------
// MODE 1: fp32 out (+bias +sinusoid PE)         [input projection]
// MODE 2: bf16 out (+bias, ReLU)                [FFN1]
// MODE 3: fp32 out (+bias + residual R)         [O-proj, FFN2]
// MODE 4: bf16 out (+bias)                      [Q, K projections]
// MODE 5: bf16 out (+bias), transposed [b,col,s] store  [V projection]
template <int MODE>
__global__ __launch_bounds__(256) void gemm_kernel(const u16* __restrict__ A,
                                                   const u16* __restrict__ Bt,
                                                   const float* __restrict__ bias,
                                                   const float* __restrict__ R,
                                                   void* __restrict__ Out,
                                                   int M, int N, int K) {
    constexpr int LDK = 40;
    __shared__ u16 As[64 * LDK];
    __shared__ u16 Bs[64 * LDK];
    int tid = threadIdx.x;
    int n0 = blockIdx.x * 64, m0 = blockIdx.y * 64;
    int w = tid >> 6, lane = tid & 63;
    int wr = (w >> 1) * 32, wc = (w & 1) * 32;
    int lr = lane & 15, lq = lane >> 4;

    v4f zero = {0.f, 0.f, 0.f, 0.f};
    v4f acc[2][2];
    acc[0][0] = zero; acc[0][1] = zero; acc[1][0] = zero; acc[1][1] = zero;

    int arow = tid >> 2, acol = (tid & 3) * 8;
    const u16* Aptr = A + (size_t)(m0 + arow) * K + acol;
    const u16* Bptr = Bt + (size_t)(n0 + arow) * K + acol;
    u16* AsW = &As[arow * LDK + acol];
    u16* BsW = &Bs[arow * LDK + acol];

    for (int k0 = 0; k0 < K; k0 += 32) {
        v8bf av = *(const v8bf*)Aptr;
        v8bf bv = *(const v8bf*)Bptr;
        __syncthreads();
        *(v8bf*)AsW = av;
        *(v8bf*)BsW = bv;
        __syncthreads();
        v8bf a0 = *(const v8bf*)&As[(wr + lr) * LDK + lq * 8];
        v8bf a1 = *(const v8bf*)&As[(wr + 16 + lr) * LDK + lq * 8];
        v8bf b0 = *(const v8bf*)&Bs[(wc + lr) * LDK + lq * 8];
        v8bf b1 = *(const v8bf*)&Bs[(wc + 16 + lr) * LDK + lq * 8];
        acc[0][0] = __builtin_amdgcn_mfma_f32_16x16x32_bf16(a0, b0, acc[0][0], 0, 0, 0);
        acc[0][1] = __builtin_amdgcn_mfma_f32_16x16x32_bf16(a0, b1, acc[0][1], 0, 0, 0);
        acc[1][0] = __builtin_amdgcn_mfma_f32_16x16x32_bf16(a1, b0, acc[1][0], 0, 0, 0);
        acc[1][1] = __builtin_amdgcn_mfma_f32_16x16x32_bf16(a1, b1, acc[1][1], 0, 0, 0);
        Aptr += 32;
        Bptr += 32;
    }

#pragma unroll
    for (int mt = 0; mt < 2; mt++) {
#pragma unroll
        for (int nt = 0; nt < 2; nt++) {
            int col = n0 + wc + nt * 16 + lr;
            float bcol = bias[col];
            if (MODE == 5) {
                int row0 = m0 + wr + mt * 16 + lq * 4;
                int bb = row0 >> 10, s0 = row0 & (S_LEN - 1);
                ushort4 o;
                o.x = f2bf(acc[mt][nt][0] + bcol);
                o.y = f2bf(acc[mt][nt][1] + bcol);
                o.z = f2bf(acc[mt][nt][2] + bcol);
                o.w = f2bf(acc[mt][nt][3] + bcol);
                *(ushort4*)((u16*)Out + ((size_t)(bb * 512 + col)) * S_LEN + s0) = o;
            } else {
#pragma unroll
                for (int reg = 0; reg < 4; reg++) {
                    int row = m0 + wr + mt * 16 + lq * 4 + reg;
                    float val = acc[mt][nt][reg] + bcol;
                    if (MODE == 1) {
                        int sPos = row & (S_LEN - 1);
                        float freq = expf((float)(col & ~1) * (-0.017988946039015984f));
                        float ang = (float)sPos * freq;
                        val += (col & 1) ? cosf(ang) : sinf(ang);
                    }
                    if (MODE == 2) val = fmaxf(val, 0.0f);
                    if (MODE == 3) val += R[(size_t)row * N + col];
                    if (MODE == 2 || MODE == 4)
                        ((u16*)Out)[(size_t)row * N + col] = f2bf(val);
                    else
                        ((float*)Out)[(size_t)row * N + col] = val;
                }
            }
        }
    }
}

// ---------------- MFMA flash attention ----------------
// Q,K bf16 [B*S][DMODEL]; Vt bf16 [B*DMODEL][S] ((b*512+h*64+d), s); O bf16 [B*S][DMODEL]
// block: 256 thr = 4 waves; wave w owns q rows qt*64+w*16 .. +16, all 64 dims of head h
#define LDT 72
__global__ __launch_bounds__(256) void fattn_kernel(const u16* __restrict__ Qg,
                                                    const u16* __restrict__ Kg,
                                                    const u16* __restrict__ Vtg,
                                                    const float* __restrict__ rb,
                                                    const int* __restrict__ lengths,
                                                    u16* __restrict__ O) {
    int qt = blockIdx.x, h = blockIdx.y, b = blockIdx.z;
    int tid = threadIdx.x, w = tid >> 6, lane = tid & 63;
    int lr = lane & 15, lq = lane >> 4;
    __shared__ u16 Ks[64 * LDT];
    __shared__ u16 Vs[64 * LDT];
    __shared__ u16 Pw[4][16 * LDT];
    __shared__ float rbs[128];
    int len = lengths[b];
    if (tid < 127) rbs[tid] = rb[h * 127 + tid];

    int qb = qt * 64 + w * 16;                     // wave q start (s index)
    size_t qgbase = ((size_t)(b * S_LEN + qb + lr)) * DMODEL + h * DK;
    v8bf qa0 = *(const v8bf*)(Qg + qgbase + lq * 8);
    v8bf qa1 = *(const v8bf*)(Qg + qgbase + 32 + lq * 8);

    v4f zero = {0.f, 0.f, 0.f, 0.f};
    v4f Oacc[4];
    Oacc[0] = zero; Oacc[1] = zero; Oacc[2] = zero; Oacc[3] = zero;
    float m_[4] = {-1e30f, -1e30f, -1e30f, -1e30f};
    float l_[4] = {0.f, 0.f, 0.f, 0.f};

    const u16* Kbase = Kg + ((size_t)b * S_LEN) * DMODEL + h * DK;
    const u16* Vbase = Vtg + ((size_t)(b * 512 + h * DK)) * S_LEN;
    const float L2E = 1.4426950408889634f;

    for (int kc = 0; kc * 64 < len; kc++) {
        __syncthreads();  // prev-iter reads done before restage
        int idx = tid;
#pragma unroll
        for (int j = 0; j < 2; j++) {
            int r = idx >> 3, c8 = idx & 7;
            v8bf kv = *(const v8bf*)(Kbase + (size_t)(kc * 64 + r) * DMODEL + c8 * 8);
            *(v8bf*)&Ks[r * LDT + c8 * 8] = kv;
            v8bf vv = *(const v8bf*)(Vbase + (size_t)r * S_LEN + kc * 64 + c8 * 8);
            *(v8bf*)&Vs[r * LDT + c8 * 8] = vv;
            idx += 256;
        }
        __syncthreads();

        // S = Q @ K^T  (16q x 64k per wave)
        v4f S[4];
#pragma unroll
        for (int nt = 0; nt < 4; nt++) {
            v8bf b0 = *(const v8bf*)&Ks[(nt * 16 + lr) * LDT + lq * 8];
            v8bf b1 = *(const v8bf*)&Ks[(nt * 16 + lr) * LDT + 32 + lq * 8];
            v4f s = __builtin_amdgcn_mfma_f32_16x16x32_bf16(qa0, b0, zero, 0, 0, 0);
            S[nt] = __builtin_amdgcn_mfma_f32_16x16x32_bf16(qa1, b1, s, 0, 0, 0);
        }

        // scale + rel bias + pad mask
        int kb0 = kc * 64;
        bool edge = (kb0 + 64 > len);
        int dmin = qb - (kb0 + 63), dmax = qb + 15 - kb0;
        bool perel = !(dmax <= -63 || dmin >= 63);
        float bconst = (dmax <= -63) ? rbs[0] : rbs[126];
#pragma unroll
        for (int nt = 0; nt < 4; nt++) {
            int k = kb0 + nt * 16 + lr;
#pragma unroll
            for (int r = 0; r < 4; r++) {
                float s = S[nt][r] * 0.125f;
                if (perel) {
                    int q = qb + lq * 4 + r;
                    int d = q - k;
                    d = d < -63 ? -63 : (d > 63 ? 63 : d);
                    s += rbs[d + 63];
                } else {
                    s += bconst;
                }
                if (edge && k >= len) s = -1e30f;
                S[nt][r] = s;
            }
        }

        // online softmax (rows fully wave-owned)
        float mnew[4], al[4];
#pragma unroll
        for (int r = 0; r < 4; r++) {
            float cm = fmaxf(fmaxf(S[0][r], S[1][r]), fmaxf(S[2][r], S[3][r]));
            cm = fmaxf(cm, __shfl_xor(cm, 1));
            cm = fmaxf(cm, __shfl_xor(cm, 2));
            cm = fmaxf(cm, __shfl_xor(cm, 4));
            cm = fmaxf(cm, __shfl_xor(cm, 8));
            float mn = fmaxf(m_[r], cm);
            al[r] = exp2f((m_[r] - mn) * L2E);
            m_[r] = mn; mnew[r] = mn;
        }
#pragma unroll
        for (int r = 0; r < 4; r++) {
            float rs = 0.f;
#pragma unroll
            for (int nt = 0; nt < 4; nt++) {
                float p = exp2f((S[nt][r] - mnew[r]) * L2E);
                Pw[w][(lq * 4 + r) * LDT + nt * 16 + lr] = f2bf(p);
                rs += p;
            }
            rs += __shfl_xor(rs, 1);
            rs += __shfl_xor(rs, 2);
            rs += __shfl_xor(rs, 4);
            rs += __shfl_xor(rs, 8);
            l_[r] = l_[r] * al[r] + rs;
            Oacc[0][r] *= al[r]; Oacc[1][r] *= al[r];
            Oacc[2][r] *= al[r]; Oacc[3][r] *= al[r];
        }

        // O += P @ V
        v8bf pa0 = *(const v8bf*)&Pw[w][lr * LDT + lq * 8];
        v8bf pa1 = *(const v8bf*)&Pw[w][lr * LDT + 32 + lq * 8];
#pragma unroll
        for (int nt = 0; nt < 4; nt++) {
            v8bf v0 = *(const v8bf*)&Vs[(nt * 16 + lr) * LDT + lq * 8];
            v8bf v1 = *(const v8bf*)&Vs[(nt * 16 + lr) * LDT + 32 + lq * 8];
            Oacc[nt] = __builtin_amdgcn_mfma_f32_16x16x32_bf16(pa0, v0, Oacc[nt], 0, 0, 0);
            Oacc[nt] = __builtin_amdgcn_mfma_f32_16x16x32_bf16(pa1, v1, Oacc[nt], 0, 0, 0);
        }
    }

    size_t obase = ((size_t)(b * S_LEN + qb)) * DMODEL + h * DK;
    float inv[4];
#pragma unroll
    for (int r = 0; r < 4; r++) inv[r] = 1.0f / l_[r];
#pragma unroll
    for (int nt = 0; nt < 4; nt++) {
#pragma unroll
        for (int r = 0; r < 4; r++) {
            O[obase + (size_t)(lq * 4 + r) * DMODEL + nt * 16 + lr] = f2bf(Oacc[nt][r] * inv[r]);
        }
    }
}

extern "C" void kernel_launch(void* const* d_in, const int* in_sizes, int n_in,
                              void* d_out, int out_size, void* d_ws, size_t ws_size,
                              hipStream_t stream) {
    const float* inputs   = (const float*)d_in[0];
    const int*   lengths  = (const int*)d_in[1];
    const float* W_in     = (const float*)d_in[2];
    const float* b_in     = (const float*)d_in[3];
    const float* Wq       = (const float*)d_in[4];
    const float* bq       = (const float*)d_in[5];
    const float* Wk       = (const float*)d_in[6];
    const float* bk       = (const float*)d_in[7];
    const float* Wv       = (const float*)d_in[8];
    const float* bv       = (const float*)d_in[9];
    const float* Wo       = (const float*)d_in[10];
    const float* bo       = (const float*)d_in[11];
    const float* rel_bias = (const float*)d_in[12];
    const float* W1       = (const float*)d_in[13];
    const float* b1       = (const float*)d_in[14];
    const float* W2       = (const float*)d_in[15];
    const float* b2       = (const float*)d_in[16];
    const float* g1       = (const float*)d_in[17];
    const float* be1      = (const float*)d_in[18];
    const float* g2       = (const float*)d_in[19];
    const float* be2      = (const float*)d_in[20];
    const float* gf       = (const float*)d_in[21];
    const float* bef      = (const float*)d_in[22];

    // ---- workspace layout ----
    char* ws = (char*)d_ws;
    float* xbuf = (float*)ws;          ws += (size_t)MROWS * DMODEL * 4;   // residual fp32
    u16* hbuf   = (u16*)ws;            ws += (size_t)MROWS * DMODEL * 2;   // LN output bf16
    u16* aobuf  = (u16*)ws;            ws += (size_t)MROWS * DMODEL * 2;   // attn output bf16
    u16* qbf    = (u16*)ws;                                                // union region (48MB):
    u16* kbf    = qbf + (size_t)MROWS * DMODEL;                            //  q/k bf16 + vt bf16
    u16* vtbf   = kbf + (size_t)MROWS * DMODEL;                            //  OR FFN intermediate
    u16* tbuf   = qbf;                 ws += (size_t)MROWS * DMODEL * 4 * 3;
    u16* inbf   = (u16*)ws;            ws += (size_t)MROWS * IN_DIM * 2;   // bf16 inputs
    u16* wt_in  = (u16*)ws;            ws += (size_t)DMODEL * IN_DIM * 2;
    u16 *wtq[2], *wtk[2], *wtv[2], *wto[2], *wt1[2], *wt2[2];
    for (int l = 0; l < 2; l++) { wtq[l] = (u16*)ws; ws += (size_t)DMODEL * DMODEL * 2; }
    for (int l = 0; l < 2; l++) { wtk[l] = (u16*)ws; ws += (size_t)DMODEL * DMODEL * 2; }
    for (int l = 0; l < 2; l++) { wtv[l] = (u16*)ws; ws += (size_t)DMODEL * DMODEL * 2; }
    for (int l = 0; l < 2; l++) { wto[l] = (u16*)ws; ws += (size_t)DMODEL * DMODEL * 2; }
    for (int l = 0; l < 2; l++) { wt1[l] = (u16*)ws; ws += (size_t)FF_DIM * DMODEL * 2; }
    for (int l = 0; l < 2; l++) { wt2[l] = (u16*)ws; ws += (size_t)DMODEL * FF_DIM * 2; }

    TArgs ta;
    int ti = 0;
    ta.d[ti++] = {W_in, wt_in, IN_DIM, DMODEL};
    for (int l = 0; l < 2; l++) ta.d[ti++] = {Wq + (size_t)l * DMODEL * DMODEL, wtq[l], DMODEL, DMODEL};
    for (int l = 0; l < 2; l++) ta.d[ti++] = {Wk + (size_t)l * DMODEL * DMODEL, wtk[l], DMODEL, DMODEL};
    for (int l = 0; l < 2; l++) ta.d[ti++] = {Wv + (size_t)l * DMODEL * DMODEL, wtv[l], DMODEL, DMODEL};
    for (int l = 0; l < 2; l++) ta.d[ti++] = {Wo + (size_t)l * DMODEL * DMODEL, wto[l], DMODEL, DMODEL};
    for (int l = 0; l < 2; l++) ta.d[ti++] = {W1 + (size_t)l * DMODEL * FF_DIM, wt1[l], DMODEL, FF_DIM};
    for (int l = 0; l < 2; l++) ta.d[ti++] = {W2 + (size_t)l * FF_DIM * DMODEL, wt2[l], FF_DIM, DMODEL};

    conv_bf16_kernel<<<dim3((MROWS * IN_DIM / 4 + 255) / 256), 256, 0, stream>>>(
        inputs, inbf, MROWS * IN_DIM / 4);
    transpose_conv_kernel<<<dim3(64, 64, 13), dim3(32, 8), 0, stream>>>(ta);

    gemm_kernel<1><<<dim3(DMODEL / 64, MROWS / 64), 256, 0, stream>>>(
        inbf, wt_in, b_in, nullptr, xbuf, MROWS, DMODEL, IN_DIM);

    for (int l = 0; l < 2; l++) {
        ln_kernel<true><<<MROWS / 4, 256, 0, stream>>>(xbuf, g1 + l * DMODEL, be1 + l * DMODEL, hbuf);
        gemm_kernel<4><<<dim3(DMODEL / 64, MROWS / 64), 256, 0, stream>>>(
            hbuf, wtq[l], bq + l * DMODEL, nullptr, qbf, MROWS, DMODEL, DMODEL);
        gemm_kernel<4><<<dim3(DMODEL / 64, MROWS / 64), 256, 0, stream>>>(
            hbuf, wtk[l], bk + l * DMODEL, nullptr, kbf, MROWS, DMODEL, DMODEL);
        gemm_kernel<5><<<dim3(DMODEL / 64, MROWS / 64), 256, 0, stream>>>(
            hbuf, wtv[l], bv + l * DMODEL, nullptr, vtbf, MROWS, DMODEL, DMODEL);
        fattn_kernel<<<dim3(S_LEN / 64, NHEAD, B_SZ), 256, 0, stream>>>(
            qbf, kbf, vtbf, rel_bias + (size_t)l * NHEAD * 127, lengths, aobuf);
        gemm_kernel<3><<<dim3(DMODEL / 64, MROWS / 64), 256, 0, stream>>>(
            aobuf, wto[l], bo + l * DMODEL, xbuf, xbuf, MROWS, DMODEL, DMODEL);
        ln_kernel<true><<<MROWS / 4, 256, 0, stream>>>(xbuf, g2 + l * DMODEL, be2 + l * DMODEL, hbuf);
        gemm_kernel<2><<<dim3(FF_DIM / 64, MROWS / 64), 256, 0, stream>>>(
            hbuf, wt1[l], b1 + l * FF_DIM, nullptr, tbuf, MROWS, FF_DIM, DMODEL);
        gemm_kernel<3><<<dim3(DMODEL / 64, MROWS / 64), 256, 0, stream>>>(
            tbuf, wt2[l], b2 + l * DMODEL, xbuf, xbuf, MROWS, DMODEL, FF_DIM);
    }
    ln_kernel<false><<<MROWS / 4, 256, 0, stream>>>(xbuf, gf, bef, d_out);
}